// Round 1
// baseline (556.890 us; speedup 1.0000x reference)
//
#include <hip/hip_runtime.h>
#include <hip/hip_bf16.h>

typedef __attribute__((ext_vector_type(8))) short short8;
typedef __attribute__((ext_vector_type(4))) float f32x4;

// ---------------- workspace layout (bytes) ----------------
// Xpad bf16 NHWC [32][58][66][256]            : 62,717,952 B
// Wq   bf16 [4][256][2304] (k = tap*256 + c)  :  4,718,592 B
// pooled f32 [32][256]                        :     32,768 B
// idx  int [32]                               :        128 B
#define XPAD_OFF   0u
#define WQ_OFF     62717952u
#define POOL_OFF   67436544u
#define IDX_OFF    67469312u

__device__ __forceinline__ void gl_lds16(const void* g, void* l) {
  __builtin_amdgcn_global_load_lds(
      (const __attribute__((address_space(1))) unsigned int*)g,
      (__attribute__((address_space(3))) unsigned int*)l, 16, 0, 0);
}

// ---- 1. global average pool: one block per (b,c), 256 threads ----
__global__ __launch_bounds__(256) void pool_kernel(const float* __restrict__ x,
                                                   float* __restrict__ pooled) {
  __shared__ float sbuf[256];
  const int bc = blockIdx.x;                 // b*256 + c
  const float* p = x + (size_t)bc * 3136;
  float s = 0.f;
  for (int i = threadIdx.x; i < 3136; i += 256) s += p[i];
  sbuf[threadIdx.x] = s;
  __syncthreads();
  for (int st = 128; st > 0; st >>= 1) {
    if (threadIdx.x < st) sbuf[threadIdx.x] += sbuf[threadIdx.x + st];
    __syncthreads();
  }
  if (threadIdx.x == 0) pooled[bc] = sbuf[0] * (1.0f / 3136.0f);
}

// ---- 2. fc1/relu/fc2 + argmax: one block per sample ----
__global__ __launch_bounds__(128) void fc_argmax_kernel(
    const float* __restrict__ pooled, const float* __restrict__ w_fc1,
    const float* __restrict__ w_fc2, const float* __restrict__ b_fc2,
    float* __restrict__ raw_out, int* __restrict__ idx) {
  __shared__ float h[65];
  __shared__ float raws[4];
  const int b = blockIdx.x, t = threadIdx.x;
  if (t < 65) {
    float s = 0.f;
    const float* pb = pooled + b * 256;
    const float* wr = w_fc1 + t * 256;
    for (int c = 0; c < 256; ++c) s += pb[c] * wr[c];
    h[t] = s > 0.f ? s : 0.f;
  }
  __syncthreads();
  if (t < 4) {
    float s = b_fc2[t];
    const float* wr = w_fc2 + t * 65;
    for (int j = 0; j < 65; ++j) s += h[j] * wr[j];
    raws[t] = s;
    raw_out[b * 4 + t] = s;
  }
  __syncthreads();
  if (t == 0) {
    int best = 0; float bv = raws[0];
    for (int k = 1; k < 4; ++k) if (raws[k] > bv) { bv = raws[k]; best = k; }
    idx[b] = best;
  }
}

// ---- 3. LSQ quantize + reorder to [k][oc][tap*256+c], bf16 ----
// dst-indexed for coalesced writes. round = rintf (ties-to-even, matches jnp.round)
__global__ __launch_bounds__(256) void quant_kernel(
    const float* __restrict__ weight, const float* __restrict__ alpha,
    __hip_bfloat16* __restrict__ Wq) {
  const unsigned d = blockIdx.x * 256u + threadIdx.x;   // 0 .. 2,359,295
  const unsigned k = d / 589824u;
  const unsigned rr = d - k * 589824u;
  const unsigned oc = rr / 2304u;
  const unsigned r2 = rr - oc * 2304u;
  const unsigned tap = r2 >> 8;          // 0..8
  const unsigned c = r2 & 255u;
  const float a = alpha[k];
  // source (original layout): k*589824 + oc*2304 + c*9 + tap
  float v = weight[(size_t)k * 589824u + oc * 2304u + c * 9u + tap] / a;
  if (rr == 0u) {                         // only flat element [k][0] is clamped
    if (k == 0u)      v = fminf(fmaxf(v, -2.f), 1.f);
    else if (k == 1u) v = fminf(fmaxf(v, -4.f), 3.f);
    else if (k == 2u) v = fminf(fmaxf(v, -8.f), 7.f);
  }
  Wq[d] = __float2bfloat16(rintf(v) * a);
}

// ---- 4. pad + NCHW->NHWC + bf16: Xpad[b][y'(0..57)][x'(0..65)][c] ----
__global__ __launch_bounds__(256) void padx_kernel(const float* __restrict__ x,
                                                   __hip_bfloat16* __restrict__ Xpad) {
  const int by = blockIdx.x;               // b*58 + y'
  const int b = by / 58, yp = by - b * 58;
  const int c = threadIdx.x;               // 0..255
  const bool rowin = (yp >= 1 && yp <= 56);
  const float* xrow = x + (((size_t)b * 256 + c) * 56 + (yp - 1)) * 56;
  __hip_bfloat16* orow = Xpad + ((size_t)by * 66) * 256 + c;
  for (int xp = 0; xp < 66; ++xp) {
    float v = 0.f;
    if (rowin && xp >= 1 && xp <= 56) v = xrow[xp - 1];
    orow[xp * 256] = __float2bfloat16(v);
  }
}

// ---- 5. conv as implicit GEMM, bf16 MFMA 16x16x32 ----
// block: 128 oc x 128 pix (2 rows x 64 padded cols), 256 threads = 4 waves (2x2)
// grid: (28 rowpairs, 2 octiles, 32 samples)
__global__ __launch_bounds__(256, 2) void conv_kernel(
    const __hip_bfloat16* __restrict__ Xpad, const __hip_bfloat16* __restrict__ Wq,
    const int* __restrict__ idx, const float* __restrict__ bias_w,
    float* __restrict__ out) {
  // Xs: [4 rows][66 cols][32 ch] = 8448 elems, padded to 8704 (17 KiB) for
  // whole-wave global_load_lds segments. Ws: [128 oc][32 ch] = 4096 elems.
  __shared__ __hip_bfloat16 Xs[8704];
  __shared__ __hip_bfloat16 Ws[4096];

  const int tid = threadIdx.x;
  const int lane = tid & 63;
  const int w = tid >> 6;        // wave id 0..3
  const int wm = w & 1;          // oc-half
  const int wn = w >> 1;         // pixel-half (row within pair)

  const int pt = blockIdx.x;     // 0..27  -> output rows 2*pt, 2*pt+1
  const int ot = blockIdx.y;     // 0..1
  const int b = blockIdx.z;      // 0..31
  const int Y0 = pt * 2;
  const int OC0 = ot * 128;
  const int kb = idx[b];

  const __hip_bfloat16* xb = Xpad + (size_t)b * (58 * 66 * 256);
  const __hip_bfloat16* wb = Wq + (size_t)kb * 589824 + (size_t)OC0 * 2304;

  f32x4 acc[4][4];
  for (int i = 0; i < 4; ++i)
    for (int j = 0; j < 4; ++j) acc[i][j] = (f32x4){0.f, 0.f, 0.f, 0.f};

  const int arow = lane & 15;
  const int kgrp = lane >> 4;    // 0..3

  for (int cb = 0; cb < 8; ++cb) {
    __syncthreads();  // all reads of Xs/Ws from previous iter done
    // stage Xs: 1056 16B-chunks + clamp-tail; 17 wave-segments of 1 KiB
    for (int s = w; s < 17; s += 4) {
      int ch = s * 64 + lane;
      if (ch > 1055) ch = 1055;           // dup into LDS pad region (never read)
      const int p = ch >> 2, cpart = ch & 3;
      const int r = p / 66, xc = p - r * 66;
      const __hip_bfloat16* g =
          xb + (((Y0 + r) * 66 + xc) * 256 + cb * 32 + cpart * 8);
      gl_lds16(g, (char*)Xs + s * 1024);  // lds base wave-uniform
    }
    for (int tap = 0; tap < 9; ++tap) {
      if (tap) __syncthreads();           // readers of Ws done
      // stage Ws: 512 chunks = 8 wave-segments
      for (int s = w; s < 8; s += 4) {
        const int ch = s * 64 + lane;
        const int oc = ch >> 2, cpart = ch & 3;
        const __hip_bfloat16* g =
            wb + (oc * 2304 + tap * 256 + cb * 32 + cpart * 8);
        gl_lds16(g, (char*)Ws + s * 1024);
      }
      __syncthreads();                     // staging visible (vmcnt drained)

      const int dy = tap / 3, dx = tap - dy * 3;
      short8 af[4], bfr[4];
      for (int i = 0; i < 4; ++i)
        af[i] = *(const short8*)&Ws[(wm * 64 + i * 16 + arow) * 32 + kgrp * 8];
      const int xsrow = (wn + dy) * 66;
      for (int j = 0; j < 4; ++j) {
        const int col = j * 16 + arow + dx;
        bfr[j] = *(const short8*)&Xs[(xsrow + col) * 32 + kgrp * 8];
      }
      for (int i = 0; i < 4; ++i)
        for (int j = 0; j < 4; ++j)
          acc[i][j] = __builtin_amdgcn_mfma_f32_16x16x32_bf16(
              af[i], bfr[j], acc[i][j], 0, 0, 0);
    }
  }

  // epilogue: D row = (lane>>4)*4 + reg (oc), D col = lane&15 (pixel)
  const float* biasb = bias_w + kb * 256 + OC0;
  for (int i = 0; i < 4; ++i) {
    const int ocbase = wm * 64 + i * 16 + (lane >> 4) * 4;
    for (int j = 0; j < 4; ++j) {
      const int pl = wn * 64 + j * 16 + (lane & 15);
      const int xcol = pl & 63;
      if (xcol < 56) {
        const int y = Y0 + (pl >> 6);
        for (int r = 0; r < 4; ++r) {
          const int oc = ocbase + r;
          out[(((size_t)b * 256 + OC0 + oc) * 56 + y) * 56 + xcol] =
              acc[i][j][r] + biasb[oc];
        }
      }
    }
  }
}

extern "C" void kernel_launch(void* const* d_in, const int* in_sizes, int n_in,
                              void* d_out, int out_size, void* d_ws, size_t ws_size,
                              hipStream_t stream) {
  const float* x      = (const float*)d_in[0];
  const float* w_fc1  = (const float*)d_in[1];
  const float* w_fc2  = (const float*)d_in[2];
  const float* b_fc2  = (const float*)d_in[3];
  const float* alpha  = (const float*)d_in[4];
  const float* weight = (const float*)d_in[5];
  const float* bias_w = (const float*)d_in[6];

  float* out = (float*)d_out;
  float* raw_out = out + (size_t)32 * 256 * 56 * 56;  // tuple: (out, raw)

  char* ws = (char*)d_ws;
  __hip_bfloat16* Xpad = (__hip_bfloat16*)(ws + XPAD_OFF);
  __hip_bfloat16* Wq   = (__hip_bfloat16*)(ws + WQ_OFF);
  float* pooled        = (float*)(ws + POOL_OFF);
  int* idx             = (int*)(ws + IDX_OFF);

  pool_kernel<<<8192, 256, 0, stream>>>(x, pooled);
  fc_argmax_kernel<<<32, 128, 0, stream>>>(pooled, w_fc1, w_fc2, b_fc2, raw_out, idx);
  quant_kernel<<<9216, 256, 0, stream>>>(weight, alpha, Wq);
  padx_kernel<<<1856, 256, 0, stream>>>(x, Xpad);
  conv_kernel<<<dim3(28, 2, 32), 256, 0, stream>>>(Xpad, Wq, idx, bias_w, out);
}

// Round 2
// 397.915 us; speedup vs baseline: 1.3995x; 1.3995x over previous
//
#include <hip/hip_runtime.h>
#include <hip/hip_bf16.h>

typedef __attribute__((ext_vector_type(8))) short short8;
typedef __attribute__((ext_vector_type(4))) float f32x4;

// ---------------- workspace layout (bytes) ----------------
// Xpad bf16 NHWC [32][58][66][256]                     : 62,717,952 B
// Wq   bf16 fragment layout [4][2][9][8][2][4][64][8]  :  4,718,592 B
// pooled f32 [32][256]                                 :     32,768 B
// idx  int [32]                                        :        128 B
#define XPAD_OFF   0u
#define WQ_OFF     62717952u
#define POOL_OFF   67436544u
#define IDX_OFF    67469312u

__device__ __forceinline__ void gl_lds16(const void* g, void* l) {
  __builtin_amdgcn_global_load_lds(
      (const __attribute__((address_space(1))) unsigned int*)g,
      (__attribute__((address_space(3))) unsigned int*)l, 16, 0, 0);
}

// ---- 1. global average pool: one block per (b,c), 256 threads ----
__global__ __launch_bounds__(256) void pool_kernel(const float* __restrict__ x,
                                                   float* __restrict__ pooled) {
  __shared__ float sbuf[256];
  const int bc = blockIdx.x;                 // b*256 + c
  const float* p = x + (size_t)bc * 3136;
  float s = 0.f;
  for (int i = threadIdx.x; i < 3136; i += 256) s += p[i];
  sbuf[threadIdx.x] = s;
  __syncthreads();
  for (int st = 128; st > 0; st >>= 1) {
    if (threadIdx.x < st) sbuf[threadIdx.x] += sbuf[threadIdx.x + st];
    __syncthreads();
  }
  if (threadIdx.x == 0) pooled[bc] = sbuf[0] * (1.0f / 3136.0f);
}

// ---- 2. fc1/relu/fc2 + argmax: one block per sample ----
__global__ __launch_bounds__(128) void fc_argmax_kernel(
    const float* __restrict__ pooled, const float* __restrict__ w_fc1,
    const float* __restrict__ w_fc2, const float* __restrict__ b_fc2,
    float* __restrict__ raw_out, int* __restrict__ idx) {
  __shared__ float h[65];
  __shared__ float raws[4];
  const int b = blockIdx.x, t = threadIdx.x;
  if (t < 65) {
    float s = 0.f;
    const float* pb = pooled + b * 256;
    const float* wr = w_fc1 + t * 256;
    for (int c = 0; c < 256; ++c) s += pb[c] * wr[c];
    h[t] = s > 0.f ? s : 0.f;
  }
  __syncthreads();
  if (t < 4) {
    float s = b_fc2[t];
    const float* wr = w_fc2 + t * 65;
    for (int j = 0; j < 65; ++j) s += h[j] * wr[j];
    raws[t] = s;
    raw_out[b * 4 + t] = s;
  }
  __syncthreads();
  if (t == 0) {
    int best = 0; float bv = raws[0];
    for (int k = 1; k < 4; ++k) if (raws[k] > bv) { bv = raws[k]; best = k; }
    idx[b] = best;
  }
}

// ---- 3. LSQ quantize + reorder to MFMA-fragment-ready layout, bf16 ----
// Wq element index: ((((((k*2+ot)*9+tap)*8+cb32)*2+wm)*4+i)*64 + kgrp*16+arow)*8 + cl
// so a wave's af[i] load (lane = kgrp*16+arow, 16B each) is a single coalesced 1KiB read.
__global__ __launch_bounds__(256) void quant_kernel(
    const float* __restrict__ weight, const float* __restrict__ alpha,
    __hip_bfloat16* __restrict__ Wq) {
  const unsigned d = blockIdx.x * 256u + threadIdx.x;   // 0 .. 2,359,295
  const unsigned cl   = d & 7u;
  const unsigned lane = (d >> 3) & 63u;
  const unsigned arow = lane & 15u;
  const unsigned kgrp = lane >> 4;
  const unsigned i    = (d >> 9) & 3u;
  const unsigned wm   = (d >> 11) & 1u;
  const unsigned cb32 = (d >> 12) & 7u;
  const unsigned rest = d >> 15;
  const unsigned tap  = rest % 9u;
  const unsigned q    = rest / 9u;
  const unsigned ot   = q & 1u;
  const unsigned k    = q >> 1;
  const unsigned oc = ot * 128u + wm * 64u + i * 16u + arow;
  const unsigned ch = cb32 * 32u + kgrp * 8u + cl;
  const float a = alpha[k];
  float v = weight[(size_t)k * 589824u + oc * 2304u + ch * 9u + tap] / a;
  if (oc == 0u && ch == 0u && tap == 0u) {  // only flat element [k][0] is clamped
    if (k == 0u)      v = fminf(fmaxf(v, -2.f), 1.f);
    else if (k == 1u) v = fminf(fmaxf(v, -4.f), 3.f);
    else if (k == 2u) v = fminf(fmaxf(v, -8.f), 7.f);
  }
  Wq[d] = __float2bfloat16(rintf(v) * a);
}

// ---- 4. pad + NCHW->NHWC + bf16 via LDS transpose ----
// grid (58, 2, 32): y' 0..57, c-half, b. block 256.
__global__ __launch_bounds__(256) void padx_kernel(const float* __restrict__ x,
                                                   __hip_bfloat16* __restrict__ Xpad) {
  __shared__ float T[56 * 132];   // [px][c_local], stride 132 (16B-aligned rows)
  const int yp = blockIdx.x;
  const int c0 = blockIdx.y * 128;
  const int b  = blockIdx.z;
  const int tid = threadIdx.x;
  __hip_bfloat16* orow = Xpad + ((size_t)(b * 58 + yp) * 66) * 256 + c0;
  const short8 zero8 = (short8){0, 0, 0, 0, 0, 0, 0, 0};
  const bool rowin = (yp >= 1 && yp <= 56);
  if (rowin) {
    const float* xbase = x + (((size_t)b * 256 + c0) * 56 + (yp - 1)) * 56;
    for (int i = tid; i < 128 * 56; i += 256) {        // coalesced along px
      const int cl = i / 56, px = i - cl * 56;
      T[px * 132 + cl] = xbase[cl * 3136 + px];
    }
    __syncthreads();
    for (int i = tid; i < 896; i += 256) {             // data cols xp=1..56
      const int px = i >> 4, cg = (i & 15) * 8;
      union { short8 v; __hip_bfloat16 e[8]; } u;
      #pragma unroll
      for (int r = 0; r < 8; ++r) u.e[r] = __float2bfloat16(T[px * 132 + cg + r]);
      *(short8*)&orow[(px + 1) * 256 + cg] = u.v;
    }
    for (int i = tid; i < 160; i += 256) {             // pad cols xp=0,57..65
      const int pi = i >> 4, cg = (i & 15) * 8;
      const int xp = (pi == 0) ? 0 : 56 + pi;
      *(short8*)&orow[xp * 256 + cg] = zero8;
    }
  } else {                                             // border rows y'=0,57
    for (int i = tid; i < 66 * 16; i += 256) {
      const int xp = i >> 4, cg = (i & 15) * 8;
      *(short8*)&orow[xp * 256 + cg] = zero8;
    }
  }
}

// ---- 5. conv as implicit GEMM, bf16 MFMA 16x16x32 ----
// block: 128 oc x 128 pix (2 rows x 64 padded cols), 4 waves (2x2)
// K-loop: 4 channel-blocks of 64; per block: stage X once (2 barriers),
// W fragments load direct global->VGPR (coalesced, L2-resident), 18 K32-steps
// (9 taps x 2 halves) software-pipelined. 288 MFMA per barrier-gap.
__global__ __launch_bounds__(256, 2) void conv_kernel(
    const __hip_bfloat16* __restrict__ Xpad, const __hip_bfloat16* __restrict__ Wq,
    const int* __restrict__ idx, const float* __restrict__ bias_w,
    float* __restrict__ out) {
  // Xs: [4 rows][66 cols][72 ch] bf16 (64 data + 8 pad for bank spread).
  // 9 x 16B chunks per pixel; chunk 8 is pad (dummy-sourced, never read).
  __shared__ __attribute__((aligned(16))) __hip_bfloat16 Xs[19456];

  const int tid = threadIdx.x;
  const int lane = tid & 63;
  const int w = tid >> 6;
  const int wm = w & 1;          // oc-half
  const int wn = w >> 1;         // pixel-half (row within pair)

  const int pt = blockIdx.x;     // 0..27 -> output rows 2*pt, 2*pt+1
  const int ot = blockIdx.y;     // 0..1
  const int b = blockIdx.z;      // 0..31
  const int Y0 = pt * 2;
  const int OC0 = ot * 128;
  const int kb = idx[b];

  const __hip_bfloat16* xb = Xpad + (size_t)b * (58 * 66 * 256);
  const short8* W0 = (const short8*)Wq + (size_t)(kb * 2 + ot) * 36864;

  f32x4 acc[4][4];
  #pragma unroll
  for (int i = 0; i < 4; ++i)
    #pragma unroll
    for (int j = 0; j < 4; ++j) acc[i][j] = (f32x4){0.f, 0.f, 0.f, 0.f};

  const int arow = lane & 15;
  const int kgrp = lane >> 4;

  for (int cc = 0; cc < 4; ++cc) {
    __syncthreads();   // previous iteration's Xs readers done
    // stage Xs: 264 pixels x 9 chunks = 2376 chunks, 38 wave-segments of 1KiB
    for (int s = w; s < 38; s += 4) {
      int ch = s * 64 + lane;
      if (ch > 2375) ch = 2375;            // tail dups land in last pixel's pad
      int p = ch / 9, cpart = ch - p * 9;
      if (cpart > 7) cpart = 7;            // pad chunk: dummy (valid) source
      const int r = p / 66, xc = p - r * 66;
      gl_lds16(xb + (((Y0 + r) * 66 + xc) * 256 + cc * 64 + cpart * 8),
               (char*)Xs + s * 1024);
    }
    __syncthreads();   // staging visible

    short8 af[4], afn[4];
    #pragma unroll
    for (int i = 0; i < 4; ++i)
      af[i] = W0[((0 * 8 + cc * 2 + 0) * 2 + wm) * 4 * 64 + i * 64 + lane];

    #pragma unroll
    for (int t = 0; t < 18; ++t) {
      const int tap = t >> 1, h = t & 1;
      const int dy = tap / 3, dx = tap - dy * 3;
      short8 bfr[4];
      const int xsrow = (wn + dy) * 66;
      #pragma unroll
      for (int j = 0; j < 4; ++j) {
        const int col = j * 16 + arow + dx;
        bfr[j] = *(const short8*)&Xs[(xsrow + col) * 72 + h * 32 + kgrp * 8];
      }
      if (t < 17) {
        const int tn = t + 1, tapn = tn >> 1, hn = tn & 1;
        #pragma unroll
        for (int i = 0; i < 4; ++i)
          afn[i] = W0[((tapn * 8 + cc * 2 + hn) * 2 + wm) * 4 * 64 + i * 64 + lane];
      }
      #pragma unroll
      for (int i = 0; i < 4; ++i)
        #pragma unroll
        for (int j = 0; j < 4; ++j)
          acc[i][j] = __builtin_amdgcn_mfma_f32_16x16x32_bf16(
              af[i], bfr[j], acc[i][j], 0, 0, 0);
      #pragma unroll
      for (int i = 0; i < 4; ++i) af[i] = afn[i];
    }
  }

  // epilogue: D row = (lane>>4)*4 + reg (oc), D col = lane&15 (pixel)
  const float* biasb = bias_w + kb * 256 + OC0;
  #pragma unroll
  for (int i = 0; i < 4; ++i) {
    const int ocbase = wm * 64 + i * 16 + (lane >> 4) * 4;
    #pragma unroll
    for (int j = 0; j < 4; ++j) {
      const int pl = wn * 64 + j * 16 + (lane & 15);
      const int xcol = pl & 63;
      if (xcol < 56) {
        const int y = Y0 + (pl >> 6);
        #pragma unroll
        for (int r = 0; r < 4; ++r) {
          const int oc = ocbase + r;
          out[(((size_t)b * 256 + OC0 + oc) * 56 + y) * 56 + xcol] =
              acc[i][j][r] + biasb[oc];
        }
      }
    }
  }
}

extern "C" void kernel_launch(void* const* d_in, const int* in_sizes, int n_in,
                              void* d_out, int out_size, void* d_ws, size_t ws_size,
                              hipStream_t stream) {
  const float* x      = (const float*)d_in[0];
  const float* w_fc1  = (const float*)d_in[1];
  const float* w_fc2  = (const float*)d_in[2];
  const float* b_fc2  = (const float*)d_in[3];
  const float* alpha  = (const float*)d_in[4];
  const float* weight = (const float*)d_in[5];
  const float* bias_w = (const float*)d_in[6];

  float* out = (float*)d_out;
  float* raw_out = out + (size_t)32 * 256 * 56 * 56;  // tuple: (out, raw)

  char* ws = (char*)d_ws;
  __hip_bfloat16* Xpad = (__hip_bfloat16*)(ws + XPAD_OFF);
  __hip_bfloat16* Wq   = (__hip_bfloat16*)(ws + WQ_OFF);
  float* pooled        = (float*)(ws + POOL_OFF);
  int* idx             = (int*)(ws + IDX_OFF);

  pool_kernel<<<8192, 256, 0, stream>>>(x, pooled);
  fc_argmax_kernel<<<32, 128, 0, stream>>>(pooled, w_fc1, w_fc2, b_fc2, raw_out, idx);
  quant_kernel<<<9216, 256, 0, stream>>>(weight, alpha, Wq);
  padx_kernel<<<dim3(58, 2, 32), 256, 0, stream>>>(x, Xpad);
  conv_kernel<<<dim3(28, 2, 32), 256, 0, stream>>>(Xpad, Wq, idx, bias_w, out);
}

// Round 3
// 372.540 us; speedup vs baseline: 1.4948x; 1.0681x over previous
//
#include <hip/hip_runtime.h>
#include <hip/hip_bf16.h>

typedef __attribute__((ext_vector_type(8))) short short8;
typedef __attribute__((ext_vector_type(4))) float f32x4;

// ---------------- workspace layout (bytes) ----------------
// Xpad bf16 NHWC [32][58][66][256]                     : 62,717,952 B
// Wq   bf16 fragment layout [4][2][9][8][2][4][64][8]  :  4,718,592 B
// pooled f32 [32][256] (SUMS, zeroed by memset)        :     32,768 B
// idx  int [32]                                        :        128 B
#define XPAD_OFF   0u
#define WQ_OFF     62717952u
#define POOL_OFF   67436544u
#define IDX_OFF    67469312u

__device__ __forceinline__ void gl_lds16(const void* g, void* l) {
  __builtin_amdgcn_global_load_lds(
      (const __attribute__((address_space(1))) unsigned int*)g,
      (__attribute__((address_space(3))) unsigned int*)l, 16, 0, 0);
}

// ---- 1. fc1/relu/fc2 + argmax: one block per sample ----
// pooled holds channel SUMS; fold the 1/3136 mean into fc1.
__global__ __launch_bounds__(128) void fc_argmax_kernel(
    const float* __restrict__ pooled, const float* __restrict__ w_fc1,
    const float* __restrict__ w_fc2, const float* __restrict__ b_fc2,
    float* __restrict__ raw_out, int* __restrict__ idx) {
  __shared__ float h[65];
  __shared__ float raws[4];
  const int b = blockIdx.x, t = threadIdx.x;
  if (t < 65) {
    float s = 0.f;
    const float* pb = pooled + b * 256;
    const float* wr = w_fc1 + t * 256;
    for (int c = 0; c < 256; ++c) s += pb[c] * wr[c];
    s *= (1.0f / 3136.0f);
    h[t] = s > 0.f ? s : 0.f;
  }
  __syncthreads();
  if (t < 4) {
    float s = b_fc2[t];
    const float* wr = w_fc2 + t * 65;
    for (int j = 0; j < 65; ++j) s += h[j] * wr[j];
    raws[t] = s;
    raw_out[b * 4 + t] = s;
  }
  __syncthreads();
  if (t == 0) {
    int best = 0; float bv = raws[0];
    for (int k = 1; k < 4; ++k) if (raws[k] > bv) { bv = raws[k]; best = k; }
    idx[b] = best;
  }
}

// ---- 2. LSQ quantize + reorder to MFMA-fragment-ready layout, bf16 ----
// Wq granule index: ((((k*2+ot)*9+tap)*8+cb32)*2+wm)*4 + i)*64 + (kgrp*16+arow),
// 8 bf16 elements per granule (cl). A wave's af[i] load is one coalesced 1KiB read.
__global__ __launch_bounds__(256) void quant_kernel(
    const float* __restrict__ weight, const float* __restrict__ alpha,
    __hip_bfloat16* __restrict__ Wq) {
  const unsigned d = blockIdx.x * 256u + threadIdx.x;   // 0 .. 2,359,295
  const unsigned cl   = d & 7u;
  const unsigned lane = (d >> 3) & 63u;
  const unsigned arow = lane & 15u;
  const unsigned kgrp = lane >> 4;
  const unsigned i    = (d >> 9) & 3u;
  const unsigned wm   = (d >> 11) & 1u;
  const unsigned cb32 = (d >> 12) & 7u;
  const unsigned rest = d >> 15;
  const unsigned tap  = rest % 9u;
  const unsigned q    = rest / 9u;
  const unsigned ot   = q & 1u;
  const unsigned k    = q >> 1;
  const unsigned oc = ot * 128u + wm * 64u + i * 16u + arow;
  const unsigned ch = cb32 * 32u + kgrp * 8u + cl;
  const float a = alpha[k];
  float v = weight[(size_t)k * 589824u + oc * 2304u + ch * 9u + tap] / a;
  if (oc == 0u && ch == 0u && tap == 0u) {  // only flat element [k][0] is clamped
    if (k == 0u)      v = fminf(fmaxf(v, -2.f), 1.f);
    else if (k == 1u) v = fminf(fmaxf(v, -4.f), 3.f);
    else if (k == 2u) v = fminf(fmaxf(v, -8.f), 7.f);
  }
  Wq[d] = __float2bfloat16(rintf(v) * a);
}

// ---- 3. pad + NCHW->NHWC + bf16 via LDS transpose, fused global-avg-pool ----
// grid (58, 2, 32): y' 0..57, c-half, b. block 256.
__global__ __launch_bounds__(256) void padx_kernel(const float* __restrict__ x,
                                                   __hip_bfloat16* __restrict__ Xpad,
                                                   float* __restrict__ pooled) {
  __shared__ float T[56 * 132];   // [px][c_local], stride 132 (16B-aligned rows)
  const int yp = blockIdx.x;
  const int c0 = blockIdx.y * 128;
  const int b  = blockIdx.z;
  const int tid = threadIdx.x;
  __hip_bfloat16* orow = Xpad + ((size_t)(b * 58 + yp) * 66) * 256 + c0;
  const short8 zero8 = (short8){0, 0, 0, 0, 0, 0, 0, 0};
  const bool rowin = (yp >= 1 && yp <= 56);
  if (rowin) {
    const float* xbase = x + (((size_t)b * 256 + c0) * 56 + (yp - 1)) * 56;
    for (int i = tid; i < 128 * 56; i += 256) {        // coalesced along px
      const int cl = i / 56, px = i - cl * 56;
      T[px * 132 + cl] = xbase[cl * 3136 + px];
    }
    __syncthreads();
    if (tid < 128) {                                   // fused pooling: column sums
      float s = 0.f;
      for (int px = 0; px < 56; ++px) s += T[px * 132 + tid];
      atomicAdd(pooled + b * 256 + c0 + tid, s);
    }
    for (int i = tid; i < 896; i += 256) {             // data cols xp=1..56
      const int px = i >> 4, cg = (i & 15) * 8;
      union { short8 v; __hip_bfloat16 e[8]; } u;
      #pragma unroll
      for (int r = 0; r < 8; ++r) u.e[r] = __float2bfloat16(T[px * 132 + cg + r]);
      *(short8*)&orow[(px + 1) * 256 + cg] = u.v;
    }
    for (int i = tid; i < 160; i += 256) {             // pad cols xp=0,57..65
      const int pi = i >> 4, cg = (i & 15) * 8;
      const int xp = (pi == 0) ? 0 : 56 + pi;
      *(short8*)&orow[xp * 256 + cg] = zero8;
    }
  } else {                                             // border rows y'=0,57
    for (int i = tid; i < 66 * 16; i += 256) {
      const int xp = i >> 4, cg = (i & 15) * 8;
      *(short8*)&orow[xp * 256 + cg] = zero8;
    }
  }
}

// ---- 4. conv as implicit GEMM, bf16 MFMA 16x16x32 ----
// block: 128 oc x 128 pix (2 rows x 64 padded cols), 4 waves (2x2), acc 4x4.
// K-loop: 8 chunks of 32 channels, Xs DOUBLE-BUFFERED: chunk cbh+1 is staged
// (global_load_lds) before computing chunk cbh, so the end-of-iter barrier's
// vmcnt(0) drain finds loads complete. W fragments stream global->VGPR
// (fragment-ready layout, coalesced, L2-resident), prefetched one tap ahead.
// Xs XOR-swizzle: granule slot = p*4 + (kgrp ^ ((p>>1)&3)) -> 2-way banks (free).
__global__ __launch_bounds__(256, 4) void conv_kernel(
    const __hip_bfloat16* __restrict__ Xpad, const __hip_bfloat16* __restrict__ Wq,
    const int* __restrict__ idx, const float* __restrict__ bias_w,
    float* __restrict__ out) {
  // 2 buffers x 1088 granules (1056 data + 32 staging-tail pad) x 16 B = 34816 B
  __shared__ __attribute__((aligned(16))) __hip_bfloat16 Xs[17408];

  const int tid = threadIdx.x;
  const int lane = tid & 63;
  const int w = tid >> 6;
  const int wm = w & 1;          // oc-half
  const int wn = w >> 1;         // pixel-half (row within pair)

  const int pt = blockIdx.x;     // 0..27 -> output rows 2*pt, 2*pt+1
  const int ot = blockIdx.y;     // 0..1
  const int b = blockIdx.z;      // 0..31
  const int Y0 = pt * 2;
  const int OC0 = ot * 128;
  const int kb = idx[b];

  const __hip_bfloat16* xb = Xpad + (size_t)b * (58 * 66 * 256);
  const short8* W0 = (const short8*)Wq + (size_t)(kb * 2 + ot) * 36864;

  f32x4 acc[4][4];
  #pragma unroll
  for (int i = 0; i < 4; ++i)
    #pragma unroll
    for (int j = 0; j < 4; ++j) acc[i][j] = (f32x4){0.f, 0.f, 0.f, 0.f};

  const int arow = lane & 15;
  const int kgrp = lane >> 4;

  // stage one 32-channel chunk (264 pixels x 4 granules = 1056, 17 wave-segs)
  auto stage = [&](int cbh, int bufsel) {
    char* dst = (char*)Xs + bufsel * 17408;
    for (int k = w; k < 17; k += 4) {
      const int s = k * 64 + lane;
      int p = s >> 2;
      if (p > 263) p = 263;                 // tail lanes -> pad slots, valid src
      const int g = (s & 3) ^ ((p >> 1) & 3);
      const int r = p / 66, xc = p - r * 66;
      gl_lds16(xb + (((Y0 + r) * 66 + xc) * 256 + cbh * 32 + g * 8),
               dst + k * 1024);
    }
  };

  stage(0, 0);
  __syncthreads();

  short8 af[4], afn[4];
  #pragma unroll
  for (int i = 0; i < 4; ++i)                       // (tap0, cbh0)
    af[i] = W0[(size_t)(wm * 256) + i * 64 + lane];

  for (int cbh = 0; cbh < 8; ++cbh) {
    const __hip_bfloat16* cur = Xs + (cbh & 1) * 8704;
    if (cbh < 7) stage(cbh + 1, (cbh + 1) & 1);     // overlapped with compute

    #pragma unroll
    for (int tap = 0; tap < 9; ++tap) {
      const int dy = tap / 3, dx = tap - dy * 3;
      short8 bfr[4];
      #pragma unroll
      for (int j = 0; j < 4; ++j) {
        const int p = (wn + dy) * 66 + j * 16 + arow + dx;
        const int slot = p * 4 + (kgrp ^ ((p >> 1) & 3));
        bfr[j] = *(const short8*)&cur[slot * 8];
      }
      if (tap < 8) {
        #pragma unroll
        for (int i = 0; i < 4; ++i)
          afn[i] = W0[(((tap + 1) * 8 + cbh) * 2 + wm) * 256 + i * 64 + lane];
      } else if (cbh < 7) {
        #pragma unroll
        for (int i = 0; i < 4; ++i)                 // (tap0, cbh+1)
          afn[i] = W0[((cbh + 1) * 2 + wm) * 256 + i * 64 + lane];
      }
      #pragma unroll
      for (int i = 0; i < 4; ++i)
        #pragma unroll
        for (int j = 0; j < 4; ++j)
          acc[i][j] = __builtin_amdgcn_mfma_f32_16x16x32_bf16(
              af[i], bfr[j], acc[i][j], 0, 0, 0);
      #pragma unroll
      for (int i = 0; i < 4; ++i) af[i] = afn[i];
    }
    __syncthreads();   // drains overlapped staging; fences readers of cur
  }

  // epilogue: D row = (lane>>4)*4 + reg (oc), D col = lane&15 (pixel)
  const float* biasb = bias_w + kb * 256 + OC0;
  #pragma unroll
  for (int i = 0; i < 4; ++i) {
    const int ocbase = wm * 64 + i * 16 + (lane >> 4) * 4;
    #pragma unroll
    for (int j = 0; j < 4; ++j) {
      const int pl = wn * 64 + j * 16 + (lane & 15);
      const int xcol = pl & 63;
      if (xcol < 56) {
        const int y = Y0 + (pl >> 6);
        #pragma unroll
        for (int r = 0; r < 4; ++r) {
          const int oc = ocbase + r;
          out[(((size_t)b * 256 + OC0 + oc) * 56 + y) * 56 + xcol] =
              acc[i][j][r] + biasb[oc];
        }
      }
    }
  }
}

extern "C" void kernel_launch(void* const* d_in, const int* in_sizes, int n_in,
                              void* d_out, int out_size, void* d_ws, size_t ws_size,
                              hipStream_t stream) {
  const float* x      = (const float*)d_in[0];
  const float* w_fc1  = (const float*)d_in[1];
  const float* w_fc2  = (const float*)d_in[2];
  const float* b_fc2  = (const float*)d_in[3];
  const float* alpha  = (const float*)d_in[4];
  const float* weight = (const float*)d_in[5];
  const float* bias_w = (const float*)d_in[6];

  float* out = (float*)d_out;
  float* raw_out = out + (size_t)32 * 256 * 56 * 56;  // tuple: (out, raw)

  char* ws = (char*)d_ws;
  __hip_bfloat16* Xpad = (__hip_bfloat16*)(ws + XPAD_OFF);
  __hip_bfloat16* Wq   = (__hip_bfloat16*)(ws + WQ_OFF);
  float* pooled        = (float*)(ws + POOL_OFF);
  int* idx             = (int*)(ws + IDX_OFF);

  hipMemsetAsync(pooled, 0, 32 * 256 * sizeof(float), stream);
  padx_kernel<<<dim3(58, 2, 32), 256, 0, stream>>>(x, Xpad, pooled);
  quant_kernel<<<9216, 256, 0, stream>>>(weight, alpha, Wq);
  fc_argmax_kernel<<<32, 128, 0, stream>>>(pooled, w_fc1, w_fc2, b_fc2, raw_out, idx);
  conv_kernel<<<dim3(28, 2, 32), 256, 0, stream>>>(Xpad, Wq, idx, bias_w, out);
}

// Round 4
// 339.539 us; speedup vs baseline: 1.6401x; 1.0972x over previous
//
#include <hip/hip_runtime.h>
#include <hip/hip_bf16.h>

typedef __attribute__((ext_vector_type(8))) short short8;
typedef __attribute__((ext_vector_type(4))) float f32x4;

// ---------------- workspace layout (bytes) ----------------
// Xpad bf16 NHWC [32][58][66][256]                     : 62,717,952 B
// Wq   bf16 fragment layout [4][2][9][8][2][4][64][8]  :  4,718,592 B
// pooled f32 [32][256] (SUMS, zeroed by memset)        :     32,768 B
// idx  int [32]                                        :        128 B
#define XPAD_OFF   0u
#define WQ_OFF     62717952u
#define POOL_OFF   67436544u
#define IDX_OFF    67469312u

__device__ __forceinline__ void gl_lds16(const void* g, void* l) {
  __builtin_amdgcn_global_load_lds(
      (const __attribute__((address_space(1))) unsigned int*)g,
      (__attribute__((address_space(3))) unsigned int*)l, 16, 0, 0);
}

// ---- 1. fc1/relu/fc2 + argmax: one block per sample ----
// pooled holds channel SUMS; fold the 1/3136 mean into fc1.
__global__ __launch_bounds__(128) void fc_argmax_kernel(
    const float* __restrict__ pooled, const float* __restrict__ w_fc1,
    const float* __restrict__ w_fc2, const float* __restrict__ b_fc2,
    float* __restrict__ raw_out, int* __restrict__ idx) {
  __shared__ float h[65];
  __shared__ float raws[4];
  const int b = blockIdx.x, t = threadIdx.x;
  if (t < 65) {
    float s = 0.f;
    const float* pb = pooled + b * 256;
    const float* wr = w_fc1 + t * 256;
    for (int c = 0; c < 256; ++c) s += pb[c] * wr[c];
    s *= (1.0f / 3136.0f);
    h[t] = s > 0.f ? s : 0.f;
  }
  __syncthreads();
  if (t < 4) {
    float s = b_fc2[t];
    const float* wr = w_fc2 + t * 65;
    for (int j = 0; j < 65; ++j) s += h[j] * wr[j];
    raws[t] = s;
    raw_out[b * 4 + t] = s;
  }
  __syncthreads();
  if (t == 0) {
    int best = 0; float bv = raws[0];
    for (int k = 1; k < 4; ++k) if (raws[k] > bv) { bv = raws[k]; best = k; }
    idx[b] = best;
  }
}

// ---- 2. LSQ quantize + reorder to MFMA-fragment-ready layout, bf16 ----
// Wq granule index: (((tap*8+cbh)*2+wm)*4+i)*64 + lane per (k,ot) slab of 36864.
__global__ __launch_bounds__(256) void quant_kernel(
    const float* __restrict__ weight, const float* __restrict__ alpha,
    __hip_bfloat16* __restrict__ Wq) {
  const unsigned d = blockIdx.x * 256u + threadIdx.x;   // 0 .. 2,359,295
  const unsigned cl   = d & 7u;
  const unsigned lane = (d >> 3) & 63u;
  const unsigned arow = lane & 15u;
  const unsigned kgrp = lane >> 4;
  const unsigned i    = (d >> 9) & 3u;
  const unsigned wm   = (d >> 11) & 1u;
  const unsigned cb32 = (d >> 12) & 7u;
  const unsigned rest = d >> 15;
  const unsigned tap  = rest % 9u;
  const unsigned q    = rest / 9u;
  const unsigned ot   = q & 1u;
  const unsigned k    = q >> 1;
  const unsigned oc = ot * 128u + wm * 64u + i * 16u + arow;
  const unsigned ch = cb32 * 32u + kgrp * 8u + cl;
  const float a = alpha[k];
  float v = weight[(size_t)k * 589824u + oc * 2304u + ch * 9u + tap] / a;
  if (oc == 0u && ch == 0u && tap == 0u) {  // only flat element [k][0] is clamped
    if (k == 0u)      v = fminf(fmaxf(v, -2.f), 1.f);
    else if (k == 1u) v = fminf(fmaxf(v, -4.f), 3.f);
    else if (k == 2u) v = fminf(fmaxf(v, -8.f), 7.f);
  }
  Wq[d] = __float2bfloat16(rintf(v) * a);
}

// ---- 3. pad + NCHW->NHWC + bf16 via LDS transpose, fused global-avg-pool ----
__global__ __launch_bounds__(256) void padx_kernel(const float* __restrict__ x,
                                                   __hip_bfloat16* __restrict__ Xpad,
                                                   float* __restrict__ pooled) {
  __shared__ float T[56 * 132];   // [px][c_local], stride 132 (16B-aligned rows)
  const int yp = blockIdx.x;
  const int c0 = blockIdx.y * 128;
  const int b  = blockIdx.z;
  const int tid = threadIdx.x;
  __hip_bfloat16* orow = Xpad + ((size_t)(b * 58 + yp) * 66) * 256 + c0;
  const short8 zero8 = (short8){0, 0, 0, 0, 0, 0, 0, 0};
  const bool rowin = (yp >= 1 && yp <= 56);
  if (rowin) {
    const float* xbase = x + (((size_t)b * 256 + c0) * 56 + (yp - 1)) * 56;
    for (int i = tid; i < 128 * 56; i += 256) {        // coalesced along px
      const int cl = i / 56, px = i - cl * 56;
      T[px * 132 + cl] = xbase[cl * 3136 + px];
    }
    __syncthreads();
    if (tid < 128) {                                   // fused pooling: column sums
      float s = 0.f;
      for (int px = 0; px < 56; ++px) s += T[px * 132 + tid];
      atomicAdd(pooled + b * 256 + c0 + tid, s);
    }
    for (int i = tid; i < 896; i += 256) {             // data cols xp=1..56
      const int px = i >> 4, cg = (i & 15) * 8;
      union { short8 v; __hip_bfloat16 e[8]; } u;
      #pragma unroll
      for (int r = 0; r < 8; ++r) u.e[r] = __float2bfloat16(T[px * 132 + cg + r]);
      *(short8*)&orow[(px + 1) * 256 + cg] = u.v;
    }
    for (int i = tid; i < 160; i += 256) {             // pad cols xp=0,57..65
      const int pi = i >> 4, cg = (i & 15) * 8;
      const int xp = (pi == 0) ? 0 : 56 + pi;
      *(short8*)&orow[xp * 256 + cg] = zero8;
    }
  } else {                                             // border rows y'=0,57
    for (int i = tid; i < 66 * 16; i += 256) {
      const int xp = i >> 4, cg = (i & 15) * 8;
      *(short8*)&orow[xp * 256 + cg] = zero8;
    }
  }
}

// ---- 4. conv as implicit GEMM, bf16 MFMA 16x16x32 ----
// block: 128 oc x 256 px (4 rows x 64 padded cols), 4 waves (wm x wn),
// WAVE TILE 64oc x 128px (acc 4x8). W VMEM demand per CU halves vs 64x64
// (af bytes/tap fixed per wave; MFMAs/tap double). K: 8 chunks of 32 ch,
// X double-buffered via global_load_lds; W frags stream global->VGPR
// (fragment-ready layout), depth-1 prefetch.
// Xs granule swizzle: slot = p*4 + (kgrp ^ ((p>>1)&3)) -> conflict-free (R3: 0).
__global__ __launch_bounds__(256, 2) void conv_kernel(
    const __hip_bfloat16* __restrict__ Xpad, const __hip_bfloat16* __restrict__ Wq,
    const int* __restrict__ idx, const float* __restrict__ bias_w,
    float* __restrict__ out) {
  // 2 buffers x 1600 granules (1584 data + 16 tail pad) x 16 B = 51200 B
  __shared__ __attribute__((aligned(16))) __hip_bfloat16 Xs[25600];

  const int tid = threadIdx.x;
  const int lane = tid & 63;
  const int w = tid >> 6;
  const int wm = w & 1;          // oc-half
  const int wn = w >> 1;         // px-half: rows {0,1} vs {2,3}

  const int pt = blockIdx.x;     // 0..13 -> output rows 4*pt .. 4*pt+3
  const int ot = blockIdx.y;     // 0..1
  const int b = blockIdx.z;      // 0..31
  const int Y0 = pt * 4;
  const int OC0 = ot * 128;
  const int kb = idx[b];

  const __hip_bfloat16* xb = Xpad + (size_t)b * (58 * 66 * 256);
  const short8* W0 = (const short8*)Wq + (size_t)(kb * 2 + ot) * 36864;

  f32x4 acc[4][8];
  #pragma unroll
  for (int i = 0; i < 4; ++i)
    #pragma unroll
    for (int j = 0; j < 8; ++j) acc[i][j] = (f32x4){0.f, 0.f, 0.f, 0.f};

  const int arow = lane & 15;
  const int kgrp = lane >> 4;

  // stage one 32-ch chunk: 6 rows x 66 px x 4 granules = 1584, 25 wave-segs
  auto stage = [&](int cbh, int bufsel) {
    char* dst = (char*)Xs + bufsel * 25600;
    for (int k = w; k < 25; k += 4) {
      const int s = k * 64 + lane;
      int p = s >> 2;
      if (p > 395) p = 395;                 // tail -> pad slots, valid src
      const int g = (s & 3) ^ ((p >> 1) & 3);
      const int r = p / 66, xc = p - r * 66;
      gl_lds16(xb + (((Y0 + r) * 66 + xc) * 256 + cbh * 32 + g * 8),
               dst + k * 1024);
    }
  };

  stage(0, 0);
  __syncthreads();

  short8 af[4], afn[4];
  #pragma unroll
  for (int i = 0; i < 4; ++i)                       // (tap0, cbh0)
    af[i] = W0[wm * 256 + i * 64 + lane];

  for (int cbh = 0; cbh < 8; ++cbh) {
    const __hip_bfloat16* cur = Xs + (cbh & 1) * 12800;
    if (cbh < 7) stage(cbh + 1, (cbh + 1) & 1);     // overlapped with compute

    #pragma unroll
    for (int tap = 0; tap < 9; ++tap) {
      const int dy = tap / 3, dx = tap - dy * 3;
      // W prefetch for next tap (depth 1)
      if (tap < 8) {
        #pragma unroll
        for (int i = 0; i < 4; ++i)
          afn[i] = W0[(((tap + 1) * 8 + cbh) * 2 + wm) * 256 + i * 64 + lane];
      } else if (cbh < 7) {
        #pragma unroll
        for (int i = 0; i < 4; ++i)                 // (tap0, cbh+1)
          afn[i] = W0[((cbh + 1) * 2 + wm) * 256 + i * 64 + lane];
      }
      // two j-groups of 4 to cap live bfr registers
      #pragma unroll
      for (int jg = 0; jg < 2; ++jg) {
        short8 bfr[4];
        #pragma unroll
        for (int jj = 0; jj < 4; ++jj) {
          const int j = jg * 4 + jj;
          const int row_local = wn * 2 + (j >> 2);
          const int col = (j & 3) * 16 + arow + dx;
          const int p = (row_local + dy) * 66 + col;
          const int slot = p * 4 + (kgrp ^ ((p >> 1) & 3));
          bfr[jj] = *(const short8*)&cur[slot * 8];
        }
        #pragma unroll
        for (int i = 0; i < 4; ++i)
          #pragma unroll
          for (int jj = 0; jj < 4; ++jj)
            acc[i][jg * 4 + jj] = __builtin_amdgcn_mfma_f32_16x16x32_bf16(
                af[i], bfr[jj], acc[i][jg * 4 + jj], 0, 0, 0);
      }
      #pragma unroll
      for (int i = 0; i < 4; ++i) af[i] = afn[i];
    }
    __syncthreads();   // drains overlapped staging; fences readers of cur
  }

  // epilogue: D row = (lane>>4)*4 + reg (oc), D col = lane&15 (pixel)
  const float* biasb = bias_w + kb * 256 + OC0;
  #pragma unroll
  for (int i = 0; i < 4; ++i) {
    const int ocbase = wm * 64 + i * 16 + (lane >> 4) * 4;
    #pragma unroll
    for (int j = 0; j < 8; ++j) {
      const int xcol = (j & 3) * 16 + (lane & 15);
      if (xcol < 56) {
        const int y = Y0 + wn * 2 + (j >> 2);
        #pragma unroll
        for (int r = 0; r < 4; ++r) {
          const int oc = ocbase + r;
          out[(((size_t)b * 256 + OC0 + oc) * 56 + y) * 56 + xcol] =
              acc[i][j][r] + biasb[oc];
        }
      }
    }
  }
}

extern "C" void kernel_launch(void* const* d_in, const int* in_sizes, int n_in,
                              void* d_out, int out_size, void* d_ws, size_t ws_size,
                              hipStream_t stream) {
  const float* x      = (const float*)d_in[0];
  const float* w_fc1  = (const float*)d_in[1];
  const float* w_fc2  = (const float*)d_in[2];
  const float* b_fc2  = (const float*)d_in[3];
  const float* alpha  = (const float*)d_in[4];
  const float* weight = (const float*)d_in[5];
  const float* bias_w = (const float*)d_in[6];

  float* out = (float*)d_out;
  float* raw_out = out + (size_t)32 * 256 * 56 * 56;  // tuple: (out, raw)

  char* ws = (char*)d_ws;
  __hip_bfloat16* Xpad = (__hip_bfloat16*)(ws + XPAD_OFF);
  __hip_bfloat16* Wq   = (__hip_bfloat16*)(ws + WQ_OFF);
  float* pooled        = (float*)(ws + POOL_OFF);
  int* idx             = (int*)(ws + IDX_OFF);

  hipMemsetAsync(pooled, 0, 32 * 256 * sizeof(float), stream);
  padx_kernel<<<dim3(58, 2, 32), 256, 0, stream>>>(x, Xpad, pooled);
  quant_kernel<<<9216, 256, 0, stream>>>(weight, alpha, Wq);
  fc_argmax_kernel<<<32, 128, 0, stream>>>(pooled, w_fc1, w_fc2, b_fc2, raw_out, idx);
  conv_kernel<<<dim3(14, 2, 32), 256, 0, stream>>>(Xpad, Wq, idx, bias_w, out);
}

// Round 5
// 336.482 us; speedup vs baseline: 1.6550x; 1.0091x over previous
//
#include <hip/hip_runtime.h>
#include <hip/hip_bf16.h>

typedef __attribute__((ext_vector_type(8))) short short8;
typedef __attribute__((ext_vector_type(16))) float f32x16;

// ---------------- workspace layout (bytes) ----------------
// Xpad bf16 NHWC [32][58][58][256]                    : 55,115,776 B
// Wq   bf16 32x32-frag layout [4][2][9][8][...]       :  4,718,592 B
// pooled f32 [32][256] (SUMS, zeroed by memset)       :     32,768 B
// idx  int [32]                                       :        128 B
#define XPAD_OFF   0u
#define WQ_OFF     55115776u
#define POOL_OFF   59834368u
#define IDX_OFF    59867136u

__device__ __forceinline__ void gl_lds16(const void* g, void* l) {
  __builtin_amdgcn_global_load_lds(
      (const __attribute__((address_space(1))) unsigned int*)g,
      (__attribute__((address_space(3))) unsigned int*)l, 16, 0, 0);
}

// ---- 1. fc1/relu/fc2 + argmax: one block per sample ----
__global__ __launch_bounds__(128) void fc_argmax_kernel(
    const float* __restrict__ pooled, const float* __restrict__ w_fc1,
    const float* __restrict__ w_fc2, const float* __restrict__ b_fc2,
    float* __restrict__ raw_out, int* __restrict__ idx) {
  __shared__ float h[65];
  __shared__ float raws[4];
  const int b = blockIdx.x, t = threadIdx.x;
  if (t < 65) {
    float s = 0.f;
    const float* pb = pooled + b * 256;
    const float* wr = w_fc1 + t * 256;
    for (int c = 0; c < 256; ++c) s += pb[c] * wr[c];
    s *= (1.0f / 3136.0f);
    h[t] = s > 0.f ? s : 0.f;
  }
  __syncthreads();
  if (t < 4) {
    float s = b_fc2[t];
    const float* wr = w_fc2 + t * 65;
    for (int j = 0; j < 65; ++j) s += h[j] * wr[j];
    raws[t] = s;
    raw_out[b * 4 + t] = s;
  }
  __syncthreads();
  if (t == 0) {
    int best = 0; float bv = raws[0];
    for (int k = 1; k < 4; ++k) if (raws[k] > bv) { bv = raws[k]; best = k; }
    idx[b] = best;
  }
}

// ---- 2. LSQ quantize + reorder to 32x32x16-fragment-ready layout ----
// slab (k,ot): granule = (tap*64 + cbh*8 + wm*4 + octile*2 + s)*64 + lane
// lane carries oc%32 (lane&31) and ch-half (lane>>5); 8 ch elems per granule.
__global__ __launch_bounds__(256) void quant_kernel(
    const float* __restrict__ weight, const float* __restrict__ alpha,
    __hip_bfloat16* __restrict__ Wq) {
  const unsigned d = blockIdx.x * 256u + threadIdx.x;   // 0 .. 2,359,295
  const unsigned cl   = d & 7u;
  const unsigned g    = d >> 3;          // granule [0, 294912)
  const unsigned lane = g & 63u;
  const unsigned u    = g >> 6;          // unit [0, 4608)
  const unsigned low  = u & 63u;
  const unsigned s      = low & 1u;
  const unsigned octile = (low >> 1) & 1u;
  const unsigned wm     = (low >> 2) & 1u;
  const unsigned cbh    = (low >> 3) & 7u;
  const unsigned t6   = u >> 6;          // slabq*9 + tap, [0, 72)
  const unsigned tap  = t6 % 9u;
  const unsigned q    = t6 / 9u;
  const unsigned ot   = q & 1u;
  const unsigned k    = q >> 1;
  const unsigned oc = ot * 128u + wm * 64u + octile * 32u + (lane & 31u);
  const unsigned ch = cbh * 32u + s * 16u + (lane >> 5) * 8u + cl;
  const float a = alpha[k];
  float v = weight[(size_t)k * 589824u + oc * 2304u + ch * 9u + tap] / a;
  if (oc == 0u && ch == 0u && tap == 0u) {  // only flat element [k][0] clamped
    if (k == 0u)      v = fminf(fmaxf(v, -2.f), 1.f);
    else if (k == 1u) v = fminf(fmaxf(v, -4.f), 3.f);
    else if (k == 2u) v = fminf(fmaxf(v, -8.f), 7.f);
  }
  Wq[d] = __float2bfloat16(rintf(v) * a);
}

// ---- 3. pad + NCHW->NHWC + bf16 via LDS transpose, fused global-avg-pool ----
// Xpad rows 58 (y'), cols 58 (x' = 0..57; input col x'-1), 256 ch.
__global__ __launch_bounds__(256) void padx_kernel(const float* __restrict__ x,
                                                   __hip_bfloat16* __restrict__ Xpad,
                                                   float* __restrict__ pooled) {
  __shared__ float T[56 * 132];   // [px][c_local], stride 132
  const int yp = blockIdx.x;
  const int c0 = blockIdx.y * 128;
  const int b  = blockIdx.z;
  const int tid = threadIdx.x;
  __hip_bfloat16* orow = Xpad + ((size_t)(b * 58 + yp) * 58) * 256 + c0;
  const short8 zero8 = (short8){0, 0, 0, 0, 0, 0, 0, 0};
  const bool rowin = (yp >= 1 && yp <= 56);
  if (rowin) {
    const float* xbase = x + (((size_t)b * 256 + c0) * 56 + (yp - 1)) * 56;
    for (int i = tid; i < 128 * 56; i += 256) {        // coalesced along px
      const int cl = i / 56, px = i - cl * 56;
      T[px * 132 + cl] = xbase[cl * 3136 + px];
    }
    __syncthreads();
    if (tid < 128) {                                   // fused pooling
      float s = 0.f;
      for (int px = 0; px < 56; ++px) s += T[px * 132 + tid];
      atomicAdd(pooled + b * 256 + c0 + tid, s);
    }
    for (int i = tid; i < 896; i += 256) {             // data cols xp=1..56
      const int px = i >> 4, cg = (i & 15) * 8;
      union { short8 v; __hip_bfloat16 e[8]; } u;
      #pragma unroll
      for (int r = 0; r < 8; ++r) u.e[r] = __float2bfloat16(T[px * 132 + cg + r]);
      *(short8*)&orow[(px + 1) * 256 + cg] = u.v;
    }
    for (int i = tid; i < 32; i += 256) {              // pad cols xp=0,57
      const int cg = (i & 15) * 8;
      const int xp = (i >> 4) ? 57 : 0;
      *(short8*)&orow[xp * 256 + cg] = zero8;
    }
  } else {                                             // border rows y'=0,57
    for (int i = tid; i < 58 * 16; i += 256) {
      const int xp = i >> 4, cg = (i & 15) * 8;
      *(short8*)&orow[xp * 256 + cg] = zero8;
    }
  }
}

// ---- 4. conv as implicit GEMM, bf16 MFMA 32x32x16 ----
// block 128oc x 256px (4 rows x 64 cols), 4 waves 2x2; wave tile 64oc x 128px
// = 2 octile x 4 pxtile of 32x32, acc 8 x f32x16 = 128 regs.
// K: 8 chunks of 32ch. X double-buffered in LDS, staging ISSUE SPREAD over
// taps 0..5 of the previous chunk (smooth HBM demand; every vmcnt wait finds
// loads >=2 taps old). W: depth-2 register ring (3 sets x 4 granules) from
// fragment-ready global layout -> all waits have ~2000cyc drain distance.
__global__ __launch_bounds__(256, 2) void conv_kernel(
    const __hip_bfloat16* __restrict__ Xpad, const __hip_bfloat16* __restrict__ Wq,
    const int* __restrict__ idx, const float* __restrict__ bias_w,
    float* __restrict__ out) {
  // per buffer: 6 rows x 58 px x 4 granules = 1392 data granules; padded to
  // 1424 granules (22784 B) to absorb discarded-lane reads (col<=65) and the
  // staging tail. 2 buffers = 45568 B.
  __shared__ __attribute__((aligned(16))) __hip_bfloat16 Xs[22784];

  const int tid = threadIdx.x;
  const int lane = tid & 63;
  const int w = tid >> 6;
  const int wm = w & 1;          // oc-half (64)
  const int wn = w >> 1;         // px-half: rows {0,1} vs {2,3}

  const int pt = blockIdx.x;     // 0..13 -> output rows 4*pt..4*pt+3
  const int ot = blockIdx.y;     // 0..1
  const int b = blockIdx.z;      // 0..31
  const int Y0 = pt * 4;
  const int OC0 = ot * 128;
  const int kb = idx[b];

  const __hip_bfloat16* xb = Xpad + (size_t)b * (58 * 58 * 256);
  const short8* W0 = (const short8*)Wq + (size_t)(kb * 2 + ot) * 36864;

  f32x16 acc[2][4];
  #pragma unroll
  for (int i = 0; i < 2; ++i)
    #pragma unroll
    for (int j = 0; j < 4; ++j)
      acc[i][j] = (f32x16){0,0,0,0,0,0,0,0,0,0,0,0,0,0,0,0};

  const int nlo = lane & 31;     // oc%32 (A) / px col (B)
  const int khalf = lane >> 5;   // ch-half selector

  // one staging segment (64 granules) of chunk cbn into buffer bufsel
  auto stageseg = [&](int cbn, int bufsel, int k) {
    int sidx = k * 64 + lane;
    int p = sidx >> 2;
    if (p > 347) p = 347;                   // tail dups -> pad granules
    const int gsel = (sidx & 3) ^ ((p >> 1) & 3);
    const int r = p / 58, xc = p - r * 58;
    gl_lds16(xb + (((Y0 + r) * 58 + xc) * 256 + cbn * 32 + gsel * 8),
             (char*)Xs + bufsel * 22784 + k * 1024);
  };

  for (int k = w; k < 22; k += 4) stageseg(0, 0, k);   // chunk 0 burst
  __syncthreads();

  // W register ring, depth 2: afr[set][octile*2+s]
  short8 afr[3][4];
  #pragma unroll
  for (int oc2 = 0; oc2 < 2; ++oc2)
    #pragma unroll
    for (int s2 = 0; s2 < 2; ++s2) {
      afr[0][oc2 * 2 + s2] = W0[0 * 4096 + 0 * 512 + wm * 256 + oc2 * 128 + s2 * 64 + lane];
      afr[1][oc2 * 2 + s2] = W0[1 * 4096 + 0 * 512 + wm * 256 + oc2 * 128 + s2 * 64 + lane];
    }

  for (int cbh = 0; cbh < 8; ++cbh) {
    const __hip_bfloat16* cur = Xs + (cbh & 1) * 11392;
    const int nb = (cbh + 1) & 1;

    #pragma unroll
    for (int t = 0; t < 9; ++t) {
      const int dy = t / 3, dx = t - dy * 3;
      // spread X staging for next chunk: ~3-4 segs per tap, taps 0..5
      if (cbh < 7) {
        if (t < 5) stageseg(cbh + 1, nb, w + 4 * t);
        else if (t == 5 && w < 2) stageseg(cbh + 1, nb, w + 20);
      }
      // W prefetch for tt+2 (depth-2 ring)
      if (cbh < 7 || t < 7) {
        const int tap2 = (t + 2) % 9, cb2 = cbh + (t + 2) / 9;
        #pragma unroll
        for (int oc2 = 0; oc2 < 2; ++oc2)
          #pragma unroll
          for (int s2 = 0; s2 < 2; ++s2)
            afr[(t + 2) % 3][oc2 * 2 + s2] =
                W0[tap2 * 4096 + cb2 * 512 + wm * 256 + oc2 * 128 + s2 * 64 + lane];
      }
      // compute: 2 K16-steps x 4 px-tiles x 2 oc-tiles
      #pragma unroll
      for (int s = 0; s < 2; ++s) {
        #pragma unroll
        for (int j = 0; j < 4; ++j) {
          const int row = wn * 2 + (j >> 1) + dy;
          const int col = (j & 1) * 32 + nlo + dx;
          const int p = row * 58 + col;
          const int slot = p * 4 + ((s * 2 + khalf) ^ ((p >> 1) & 3));
          const short8 bfr = *(const short8*)&cur[slot * 8];
          #pragma unroll
          for (int i = 0; i < 2; ++i)
            acc[i][j] = __builtin_amdgcn_mfma_f32_32x32x16_bf16(
                afr[t % 3][i * 2 + s], bfr, acc[i][j], 0, 0, 0);
        }
      }
    }
    __syncthreads();   // staging of next chunk complete; cur readers done
  }

  // epilogue: 32x32 C/D: col=lane&31, row=(reg&3)+8*(reg>>2)+4*(lane>>5)
  const float* biasb = bias_w + kb * 256;
  #pragma unroll
  for (int i = 0; i < 2; ++i) {
    #pragma unroll
    for (int j = 0; j < 4; ++j) {
      const int xcol = (j & 1) * 32 + nlo;
      if (xcol < 56) {
        const int y = Y0 + wn * 2 + (j >> 1);
        #pragma unroll
        for (int reg = 0; reg < 16; ++reg) {
          const int row = (reg & 3) + 8 * (reg >> 2) + 4 * khalf;
          const int oc = OC0 + wm * 64 + i * 32 + row;
          out[(((size_t)b * 256 + oc) * 56 + y) * 56 + xcol] =
              acc[i][j][reg] + biasb[oc];
        }
      }
    }
  }
}

extern "C" void kernel_launch(void* const* d_in, const int* in_sizes, int n_in,
                              void* d_out, int out_size, void* d_ws, size_t ws_size,
                              hipStream_t stream) {
  const float* x      = (const float*)d_in[0];
  const float* w_fc1  = (const float*)d_in[1];
  const float* w_fc2  = (const float*)d_in[2];
  const float* b_fc2  = (const float*)d_in[3];
  const float* alpha  = (const float*)d_in[4];
  const float* weight = (const float*)d_in[5];
  const float* bias_w = (const float*)d_in[6];

  float* out = (float*)d_out;
  float* raw_out = out + (size_t)32 * 256 * 56 * 56;  // tuple: (out, raw)

  char* ws = (char*)d_ws;
  __hip_bfloat16* Xpad = (__hip_bfloat16*)(ws + XPAD_OFF);
  __hip_bfloat16* Wq   = (__hip_bfloat16*)(ws + WQ_OFF);
  float* pooled        = (float*)(ws + POOL_OFF);
  int* idx             = (int*)(ws + IDX_OFF);

  hipMemsetAsync(pooled, 0, 32 * 256 * sizeof(float), stream);
  padx_kernel<<<dim3(58, 2, 32), 256, 0, stream>>>(x, Xpad, pooled);
  quant_kernel<<<9216, 256, 0, stream>>>(weight, alpha, Wq);
  fc_argmax_kernel<<<32, 128, 0, stream>>>(pooled, w_fc1, w_fc2, b_fc2, raw_out, idx);
  conv_kernel<<<dim3(14, 2, 32), 256, 0, stream>>>(Xpad, Wq, idx, bias_w, out);
}